// Round 13
// baseline (363.431 us; speedup 1.0000x reference)
//
#include <hip/hip_runtime.h>
#include <math.h>

// Problem constants
#define B 64
#define D 2048
#define H 4096
#define NSEED 50000
#define KTOP 50
#define NCAND 64            // rescored candidates per row
#define CEMIT 20            // candidates emitted per chunk (P(chunk holds >20 of top-64) ~ 2e-20)
#define NCHUNKS 64          // topk chunks per row
#define CHUNK_SZ 782        // ceil(50000/64)

// ws layout (float offsets)
#define WS_LOGITS   0                         // 64*50000 = 3,200,000 (also MLP partials)
#define WS_H        3200000                   // 64*4096  = 262,144
#define WS_Q2       (WS_H + B*H)              // 64*2048  = 131,072
#define WS_PART     (WS_Q2 + B*D)             // 1,048,576 (cand/rvals/tidx live here)
#define WS_CVAL     (WS_PART + 1048576)       // 64*64*20 = 81,920 (region sized 262,144)
#define WS_CIDX     (WS_CVAL + 262144)        // ints
#define WS_CM       (WS_CIDX + 262144)        // 4096
#define WS_CS       (WS_CM + 4096)            // 4096
#define WS_RM       (WS_CS + 4096)            // 64
#define WS_RS       (WS_RM + 64)              // 64
#define WS_Q2HL     (WS_RS + 64)              // q2hg+q2lg: 2*131072 ushorts = 131,072 floats
// sub-allocations inside the PART region:
#define WSP_CAND    200000                    // 64*64 ints
#define WSP_RVAL    220000                    // 64*64 floats
#define WSP_TIDX    240000                    // 64*50 ints

typedef short s16x8 __attribute__((ext_vector_type(8)));
typedef float f32x4 __attribute__((ext_vector_type(4)));

// ---------------------------------------------------------------------------
// bf16 split helpers (RNE, used on the q2 producer path)
// ---------------------------------------------------------------------------
__device__ __forceinline__ unsigned short bf16_rne(float x)
{
    unsigned int b = __float_as_uint(x);
    b += 0x7FFFu + ((b >> 16) & 1u);
    return (unsigned short)(b >> 16);
}
__device__ __forceinline__ float bf16_tof(unsigned short h)
{
    return __uint_as_float(((unsigned int)h) << 16);
}

// ---------------------------------------------------------------------------
// MLP GEMM, pipelined fp32 (kept fp32 deliberately — q2 accuracy gates the
// topk-index ordering). C_partial[kc][64][N] = A[64][Kc] @ W[Kc][N]
// (exact round-7 configuration — known-good)
// ---------------------------------------------------------------------------
__global__ __launch_bounds__(256) void gemm64p_kernel(
    const float* __restrict__ A, const float* __restrict__ W,
    float* __restrict__ part, int K, int N, int kcK, int nBlocks)
{
    __shared__ float As[2][32][68];   // [buf][k][m]
    __shared__ float Bs[2][32][68];   // [buf][k][n]

    const int tid = threadIdx.x;
    const int nb = blockIdx.x % nBlocks;
    const int kc = blockIdx.x / nBlocks;
    const int kbeg = kc * kcK;

    const int tidm = tid >> 4;          // 0..15
    const int tidn = tid & 15;          // 0..15
    const int m0 = tidm * 4;
    const int n0 = tidn * 4;

    const int ar0 = tid >> 3, ac0 = tid & 7;    // + second A float4 at row ar0+32
    const int wr0 = tid >> 4, wc0 = tid & 15;   // + second B float4 at k-row wr0+16

    const float* Aptr0 = A + (size_t)ar0 * K + kbeg + ac0 * 4;
    const float* Aptr1 = A + (size_t)(ar0 + 32) * K + kbeg + ac0 * 4;
    const float* Wptr0 = W + (size_t)(kbeg + wr0) * N + nb * 64 + wc0 * 4;
    const float* Wptr1 = W + (size_t)(kbeg + wr0 + 16) * N + nb * 64 + wc0 * 4;

    float acc[4][4];
#pragma unroll
    for (int i = 0; i < 4; ++i)
#pragma unroll
        for (int j = 0; j < 4; ++j) acc[i][j] = 0.f;

    float4 pa0 = *(const float4*)(Aptr0);
    float4 pa1 = *(const float4*)(Aptr1);
    float4 pb0 = *(const float4*)(Wptr0);
    float4 pb1 = *(const float4*)(Wptr1);

    const int nsteps = kcK / 32;
    for (int s = 0; s < nsteps; ++s) {
        const int buf = s & 1;
        As[buf][ac0 * 4 + 0][ar0] = pa0.x;
        As[buf][ac0 * 4 + 1][ar0] = pa0.y;
        As[buf][ac0 * 4 + 2][ar0] = pa0.z;
        As[buf][ac0 * 4 + 3][ar0] = pa0.w;
        As[buf][ac0 * 4 + 0][ar0 + 32] = pa1.x;
        As[buf][ac0 * 4 + 1][ar0 + 32] = pa1.y;
        As[buf][ac0 * 4 + 2][ar0 + 32] = pa1.z;
        As[buf][ac0 * 4 + 3][ar0 + 32] = pa1.w;
        *(float4*)&Bs[buf][wr0][wc0 * 4] = pb0;
        *(float4*)&Bs[buf][wr0 + 16][wc0 * 4] = pb1;
        if (s + 1 < nsteps) {
            const int ko = 32 * (s + 1);
            pa0 = *(const float4*)(Aptr0 + ko);
            pa1 = *(const float4*)(Aptr1 + ko);
            pb0 = *(const float4*)(Wptr0 + (size_t)ko * N);
            pb1 = *(const float4*)(Wptr1 + (size_t)ko * N);
        }
        __syncthreads();
#pragma unroll
        for (int kk = 0; kk < 32; ++kk) {
            float4 a = *(const float4*)&As[buf][kk][m0];
            float4 b = *(const float4*)&Bs[buf][kk][n0];
            float av[4] = {a.x, a.y, a.z, a.w};
            float bv[4] = {b.x, b.y, b.z, b.w};
#pragma unroll
            for (int i = 0; i < 4; ++i)
#pragma unroll
                for (int j = 0; j < 4; ++j)
                    acc[i][j] += av[i] * bv[j];
        }
    }

#pragma unroll
    for (int i = 0; i < 4; ++i) {
        float4 v;
        v.x = acc[i][0]; v.y = acc[i][1]; v.z = acc[i][2]; v.w = acc[i][3];
        *(float4*)(part + (size_t)(kc * B + m0 + i) * N + nb * 64 + n0) = v;
    }
}

// Reduce K-chunk partials + bias (+ optional exact GELU).
// When uh/ul are non-null (layer 2): emits the bf16 hi/lo split of out in
// MFMA-FRAGMENT ORDER: for element (row r, col c):
//   p=c>>6, kk=c&63, KS=kk>>5, lg=(kk>>3)&3, e=kk&7, t=r>>4, l15=r&15
//   idx = p*4096 + ((KS*4+t)*64 + lg*16 + l15)*8 + e
// so a wave's fragment read (64 lanes x 16B) is one contiguous 1KB block.
__global__ void mlp_reduce_kernel(const float* __restrict__ part,
                                  const float* __restrict__ bias,
                                  float* __restrict__ out, int N, int nchunks, int gelu,
                                  unsigned short* __restrict__ uh,
                                  unsigned short* __restrict__ ul)
{
    int e = blockIdx.x * 256 + threadIdx.x;   // over B*N
    int b = e / N, j = e - b * N;
    float s = bias[j];
    for (int c = 0; c < nchunks; ++c)
        s += part[(size_t)(c * B + b) * N + j];
    if (gelu)
        s = 0.5f * s * (1.0f + erff(s * 0.70710678118654752f));
    out[e] = s;
    if (uh) {
        unsigned short hv = bf16_rne(s);
        unsigned short lv = bf16_rne(s - bf16_tof(hv));
        const int p = j >> 6, kk = j & 63;
        const int KS = kk >> 5, lg = (kk >> 3) & 3, ee = kk & 7;
        const int t = b >> 4, l15 = b & 15;
        const size_t idx = (size_t)p * 4096 + ((size_t)((KS * 4 + t) * 64 + lg * 16 + l15)) * 8 + ee;
        uh[idx] = hv;
        ul[idx] = lv;
    }
}

// int64-layout hedge for vritti_types (values 0..4 -> high words all zero)
__device__ __forceinline__ bool types_is_i64(const int* t)
{
    int acc = 0;
#pragma unroll
    for (int j = 0; j < 16; ++j) acc |= t[2 * j + 1];
    return acc == 0;
}

// ---------------------------------------------------------------------------
// sims via split-bf16 MFMA — BARRIER-FREE, LDS-FREE (round-8 idea, fixed):
// A fragments are read DIRECTLY from fragment-ordered q2 in global/L2 —
// with the r12 producer-side reorder, a wave's fragment read is 64 lanes x
// 16 B CONTIGUOUS (one 1KB L2 transaction), unlike r8's 4KB-strided scatter
// that caused the 4.9% MfmaUtil failure. No LDS, no __syncthreads, no vmcnt
// drains: waves free-run; 4 blocks/CU x 4 waves of independent streams hide
// L2 (~250cyc) and HBM (~900cyc) latency. A reuse costs 1.6GB of L2
// (~46us @34.5TB/s) concurrent with the ~210MB seed HBM stream (L3 absorbs
// the rest per r8 FETCH counters).
// grid = 782 (64-col tiles), 256 threads = 4 waves; wave w owns 16 seed cols.
// B (seed) prefetched one 64-K phase ahead in registers.
// ---------------------------------------------------------------------------
__global__ __launch_bounds__(256, 4) void sims_mfma_kernel(
    const unsigned short* __restrict__ q2hg, const unsigned short* __restrict__ q2lg,
    const float* __restrict__ seed,
    const float* __restrict__ karma, const int* __restrict__ types,
    const float* __restrict__ vbias, float* __restrict__ logits)
{
    const int tid = threadIdx.x;
    const int n0 = blockIdx.x * 64;
    const int lane = tid & 63;
    const int wv  = tid >> 6;       // 0..3
    const int l15 = lane & 15;
    const int lg  = lane >> 4;      // 0..3

    const int nrow = n0 + wv * 16 + l15;            // seed row this lane owns
    const bool nvalid = nrow < NSEED;
    const float* brow = seed + (size_t)nrow * D + 8 * lg;
    const unsigned short* qh = q2hg + (size_t)lane * 8;   // + p*4096 + frag*512
    const unsigned short* ql = q2lg + (size_t)lane * 8;

    f32x4 acc[4];
#pragma unroll
    for (int t = 0; t < 4; ++t) acc[t] = (f32x4){0.f, 0.f, 0.f, 0.f};

    // truncation split of 8 B floats -> bf16 hi/lo, pair-packed
#define SIMS_CONV(F0, F1, BH, BL)                                          \
    {                                                                      \
        union { unsigned int w[4]; s16x8 v; } uh_, ul_;                    \
        float xs[8] = {F0.x, F0.y, F0.z, F0.w, F1.x, F1.y, F1.z, F1.w};    \
        _Pragma("unroll")                                                  \
        for (int j = 0; j < 4; ++j) {                                      \
            unsigned int u0 = __float_as_uint(xs[2 * j]);                  \
            unsigned int u1 = __float_as_uint(xs[2 * j + 1]);              \
            unsigned int h0 = u0 & 0xFFFF0000u;                            \
            unsigned int h1 = u1 & 0xFFFF0000u;                            \
            uh_.w[j] = (u0 >> 16) | h1;                                    \
            float r0 = xs[2 * j]     - __uint_as_float(h0);                \
            float r1 = xs[2 * j + 1] - __uint_as_float(h1);                \
            ul_.w[j] = (__float_as_uint(r0) >> 16)                         \
                     | (__float_as_uint(r1) & 0xFFFF0000u);                \
        }                                                                  \
        BH = uh_.v; BL = ul_.v;                                            \
    }

    // B regs for current phase (k offsets +0,+4,+32,+36 from phase base)
    float4 c0, c1, c2, c3;
    c0 = c1 = c2 = c3 = make_float4(0.f, 0.f, 0.f, 0.f);
    if (nvalid) {
        c0 = *(const float4*)(brow);      c1 = *(const float4*)(brow + 4);
        c2 = *(const float4*)(brow + 32); c3 = *(const float4*)(brow + 36);
    }

    for (int p = 0; p < 32; ++p) {
        // issue ALL 16 A-fragment loads for this phase (coalesced 1KB each)
        const unsigned short* qhp = qh + (size_t)p * 4096;
        const unsigned short* qlp = ql + (size_t)p * 4096;
        s16x8 ah0[4], al0[4], ah1[4], al1[4];
#pragma unroll
        for (int t = 0; t < 4; ++t) {
            ah0[t] = *(const s16x8*)(qhp + (size_t)t * 512);
            al0[t] = *(const s16x8*)(qlp + (size_t)t * 512);
        }
#pragma unroll
        for (int t = 0; t < 4; ++t) {
            ah1[t] = *(const s16x8*)(qhp + (size_t)(4 + t) * 512);
            al1[t] = *(const s16x8*)(qlp + (size_t)(4 + t) * 512);
        }
        // B prefetch for phase p+1
        float4 na = make_float4(0.f, 0.f, 0.f, 0.f), nb = na, nc = na, nd = na;
        if (p < 31 && nvalid) {
            const int kb = (p + 1) * 64;
            na = *(const float4*)(brow + kb);      nb = *(const float4*)(brow + kb + 4);
            nc = *(const float4*)(brow + kb + 32); nd = *(const float4*)(brow + kb + 36);
        }
        // KS=0 half
        {
            s16x8 bh, bl;
            SIMS_CONV(c0, c1, bh, bl);
#pragma unroll
            for (int t = 0; t < 4; ++t) {
                acc[t] = __builtin_amdgcn_mfma_f32_16x16x32_bf16(ah0[t], bh, acc[t], 0, 0, 0);
                acc[t] = __builtin_amdgcn_mfma_f32_16x16x32_bf16(al0[t], bh, acc[t], 0, 0, 0);
                acc[t] = __builtin_amdgcn_mfma_f32_16x16x32_bf16(ah0[t], bl, acc[t], 0, 0, 0);
            }
        }
        // KS=1 half
        {
            s16x8 bh, bl;
            SIMS_CONV(c2, c3, bh, bl);
#pragma unroll
            for (int t = 0; t < 4; ++t) {
                acc[t] = __builtin_amdgcn_mfma_f32_16x16x32_bf16(ah1[t], bh, acc[t], 0, 0, 0);
                acc[t] = __builtin_amdgcn_mfma_f32_16x16x32_bf16(al1[t], bh, acc[t], 0, 0, 0);
                acc[t] = __builtin_amdgcn_mfma_f32_16x16x32_bf16(ah1[t], bl, acc[t], 0, 0, 0);
            }
        }
        c0 = na; c1 = nb; c2 = nc; c3 = nd;
    }
#undef SIMS_CONV

    // epilogue: gate + vritti bias. D layout: col=lane&15, row=4*lg+reg.
    if (nvalid) {
        const bool i64 = types_is_i64(types);
        float ka = karma[nrow];
        float gate = 1.0f / (1.0f + expf(-(ka + 0.3f) * 10.0f));
        int ty = i64 ? types[2 * nrow] : types[nrow];
        float bias = vbias[ty];
#pragma unroll
        for (int t = 0; t < 4; ++t) {
#pragma unroll
            for (int r = 0; r < 4; ++r) {
                int m = t * 16 + lg * 4 + r;
                logits[(size_t)m * NSEED + nrow] = acc[t][r] * gate + bias;
            }
        }
    }
}

// ---------------------------------------------------------------------------
// Per-(row,chunk): online softmax partial (m,s) + chunk top-CEMIT.
// grid = 64 rows * 64 chunks, 64 threads (1 wave).
// ---------------------------------------------------------------------------
__global__ __launch_bounds__(64) void chunk_topk_kernel(
    const float* __restrict__ logits,
    float* __restrict__ chunk_m, float* __restrict__ chunk_s,
    float* __restrict__ cand_val, int* __restrict__ cand_idx)
{
    const int bid = blockIdx.x;
    const int row = bid >> 6, chunk = bid & 63;
    const int start = chunk * CHUNK_SZ;
    const int end = min(start + CHUNK_SZ, NSEED);
    const int lane = threadIdx.x;
    const float* Lrow = logits + (size_t)row * NSEED;

    float v[13];
#pragma unroll
    for (int j = 0; j < 13; ++j) {
        int e = start + lane + j * 64;
        v[j] = (e < end) ? Lrow[e] : -INFINITY;
    }

    // online (m, s) partial: s = sum exp(2*(l - m))
    float m = v[0];
#pragma unroll
    for (int j = 1; j < 13; ++j) m = fmaxf(m, v[j]);
    float s = 0.f;
#pragma unroll
    for (int j = 0; j < 13; ++j) s += expf(2.f * (v[j] - m));
#pragma unroll
    for (int d = 1; d < 64; d <<= 1) {
        float mo = __shfl_xor(m, d);
        float so = __shfl_xor(s, d);
        float nm = fmaxf(m, mo);
        s = s * expf(2.f * (m - nm)) + so * expf(2.f * (mo - nm));
        m = nm;
    }
    if (lane == 0) { chunk_m[bid] = m; chunk_s[bid] = s; }

    // chunk top-CEMIT via wave-argmax iterations (lower index wins ties)
    for (int it = 0; it < CEMIT; ++it) {
        float bv = v[0]; int bj = 0;
#pragma unroll
        for (int j = 1; j < 13; ++j)
            if (v[j] > bv) { bv = v[j]; bj = j; }
        int bi = start + lane + bj * 64;
#pragma unroll
        for (int d = 1; d < 64; d <<= 1) {
            float ov = __shfl_xor(bv, d);
            int oi = __shfl_xor(bi, d);
            if (ov > bv || (ov == bv && oi < bi)) { bv = ov; bi = oi; }
        }
        if (lane == 0) {
            cand_val[bid * CEMIT + it] = bv;
            cand_idx[bid * CEMIT + it] = bi;
        }
#pragma unroll
        for (int j = 0; j < 13; ++j)
            if (start + lane + j * 64 == bi) v[j] = -INFINITY;
    }
}

// ---------------------------------------------------------------------------
// Per-row merge: 64 (m,s) partials -> (M, 1/S); 1280 candidates -> top-NCAND
// candidate indices (by MFMA logit; candidate set, not final order).
// ---------------------------------------------------------------------------
__global__ __launch_bounds__(256) void merge_topk_kernel(
    const float* __restrict__ chunk_m, const float* __restrict__ chunk_s,
    const float* __restrict__ cand_val, const int* __restrict__ cand_idx,
    float* __restrict__ row_M, float* __restrict__ row_rS,
    int* __restrict__ cand2)
{
    const int row = blockIdx.x;
    const int tid = threadIdx.x;
    const int lane = tid & 63, wave = tid >> 6;
    __shared__ float rv[4];
    __shared__ int ri[4];

    if (wave == 0) {
        float m = chunk_m[row * 64 + lane];
        float s = chunk_s[row * 64 + lane];
#pragma unroll
        for (int d = 1; d < 64; d <<= 1) {
            float mo = __shfl_xor(m, d);
            float so = __shfl_xor(s, d);
            float nm = fmaxf(m, mo);
            s = s * expf(2.f * (m - nm)) + so * expf(2.f * (mo - nm));
            m = nm;
        }
        if (lane == 0) { row_M[row] = m; row_rS[row] = 1.0f / s; }
    }

    float v[5]; int ix[5];
#pragma unroll
    for (int j = 0; j < 5; ++j) {
        int e = tid + j * 256;                      // 1280 = NCHUNKS*CEMIT
        v[j] = cand_val[row * (NCHUNKS * CEMIT) + e];
        ix[j] = cand_idx[row * (NCHUNKS * CEMIT) + e];
    }

    for (int it = 0; it < NCAND; ++it) {
        float bv = v[0]; int bi = ix[0];
#pragma unroll
        for (int j = 1; j < 5; ++j)
            if (v[j] > bv || (v[j] == bv && ix[j] < bi)) { bv = v[j]; bi = ix[j]; }
#pragma unroll
        for (int d = 1; d < 64; d <<= 1) {
            float ov = __shfl_xor(bv, d);
            int oi = __shfl_xor(bi, d);
            if (ov > bv || (ov == bv && oi < bi)) { bv = ov; bi = oi; }
        }
        if (lane == 0) { rv[wave] = bv; ri[wave] = bi; }
        __syncthreads();
        float wv = rv[0]; int wi = ri[0];
#pragma unroll
        for (int w = 1; w < 4; ++w)
            if (rv[w] > wv || (rv[w] == wv && ri[w] < wi)) { wv = rv[w]; wi = ri[w]; }
        __syncthreads();
        if (tid == 0) cand2[row * NCAND + it] = wi;
#pragma unroll
        for (int j = 0; j < 5; ++j)
            if (ix[j] == wi) v[j] = -INFINITY;
    }
}

// ---------------------------------------------------------------------------
// Exact rescore of candidates: fp64 dot(q2[row], seed[idx]) + fp32 gate/bias.
// grid = (NCAND/4, 64 rows), 256 threads = 4 waves (one candidate per wave).
// ---------------------------------------------------------------------------
__global__ __launch_bounds__(256) void rescore_kernel(
    const float* __restrict__ q2, const float* __restrict__ seed,
    const float* __restrict__ karma, const int* __restrict__ types,
    const float* __restrict__ vbias, const int* __restrict__ cand2,
    float* __restrict__ rvals)
{
    const int row = blockIdx.y;
    const int wv = threadIdx.x >> 6, lane = threadIdx.x & 63;
    const int ci = blockIdx.x * 4 + wv;             // 0..NCAND-1
    const int idx = cand2[row * NCAND + ci];
    const float* qrow = q2 + (size_t)row * D;
    const float* srow = seed + (size_t)idx * D;

    double s = 0.0;
#pragma unroll
    for (int i = 0; i < 8; ++i) {
        float4 a = *(const float4*)(qrow + lane * 4 + i * 256);
        float4 b = *(const float4*)(srow + lane * 4 + i * 256);
        s += (double)a.x * (double)b.x + (double)a.y * (double)b.y
           + (double)a.z * (double)b.z + (double)a.w * (double)b.w;
    }
#pragma unroll
    for (int d = 1; d < 64; d <<= 1) s += __shfl_xor(s, d);

    if (lane == 0) {
        float ka = karma[idx];
        float gate = 1.0f / (1.0f + expf(-(ka + 0.3f) * 10.0f));
        bool i64 = types_is_i64(types);
        int ty = i64 ? types[2 * idx] : types[idx];
        rvals[row * NCAND + ci] = (float)s * gate + vbias[ty];
    }
}

// ---------------------------------------------------------------------------
// Final per-row top-50 (sorted desc, lower index on ties) from NCAND rescored.
// grid = 64, 64 threads (1 wave, one candidate per lane).
// ---------------------------------------------------------------------------
__global__ __launch_bounds__(64) void final50_kernel(
    const float* __restrict__ rvals, const int* __restrict__ cand2,
    float* __restrict__ out_idx_f, int* __restrict__ topk_idx)
{
    const int row = blockIdx.x;
    const int lane = threadIdx.x;

    float v = rvals[row * NCAND + lane];
    int ix = cand2[row * NCAND + lane];

    for (int it = 0; it < KTOP; ++it) {
        float bv = v; int bi = ix;
#pragma unroll
        for (int d = 1; d < 64; d <<= 1) {
            float ov = __shfl_xor(bv, d);
            int oi = __shfl_xor(bi, d);
            if (ov > bv || (ov == bv && oi < bi)) { bv = ov; bi = oi; }
        }
        if (lane == 0) {
            out_idx_f[row * KTOP + it] = (float)bi;
            topk_idx[row * KTOP + it] = bi;
        }
        if (ix == bi) v = -INFINITY;
    }
}

// attention weights: w = exp(2*(l - M)) / S
__global__ void weights_kernel(const float* __restrict__ logits,
                               const float* __restrict__ row_M,
                               const float* __restrict__ row_rS,
                               float* __restrict__ attn)
{
    const int row = blockIdx.y;
    const int f = blockIdx.x * 256 + threadIdx.x;
    if (f >= NSEED / 4) return;
    const float M = row_M[row], rS = row_rS[row];
    float4 l = ((const float4*)(logits + (size_t)row * NSEED))[f];
    float4 w;
    w.x = expf(2.f * (l.x - M)) * rS;
    w.y = expf(2.f * (l.y - M)) * rS;
    w.z = expf(2.f * (l.z - M)) * rS;
    w.w = expf(2.f * (l.w - M)) * rS;
    ((float4*)(attn + (size_t)row * NSEED))[f] = w;
}

// chitta gather: 2048 floats per (row,k)
__global__ void gather_kernel(const float* __restrict__ seed,
                              const int* __restrict__ topk_idx,
                              float* __restrict__ chitta)
{
    const int k = blockIdx.x, row = blockIdx.y;
    const int idx = topk_idx[row * KTOP + k];
    const float4* src = (const float4*)(seed + (size_t)idx * D);
    float4* dst = (float4*)(chitta + (size_t)(row * KTOP + k) * D);
#pragma unroll
    for (int j = 0; j < 2; ++j)
        dst[threadIdx.x + j * 256] = src[threadIdx.x + j * 256];
}

extern "C" void kernel_launch(void* const* d_in, const int* in_sizes, int n_in,
                              void* d_out, int out_size, void* d_ws, size_t ws_size,
                              hipStream_t stream)
{
    const float* query = (const float*)d_in[0];
    const int*   types = (const int*)d_in[1];
    const float* seed  = (const float*)d_in[2];
    const float* karma = (const float*)d_in[3];
    const float* vbias = (const float*)d_in[4];
    const float* W1    = (const float*)d_in[5];
    const float* b1    = (const float*)d_in[6];
    const float* W2    = (const float*)d_in[7];
    const float* b2    = (const float*)d_in[8];

    float* ws = (float*)d_ws;
    float* logits = ws + WS_LOGITS;   // also MLP partial buffer (freed before sims)
    float* h      = ws + WS_H;
    float* q2     = ws + WS_Q2;
    float* part   = ws + WS_PART;
    float* cval   = ws + WS_CVAL;
    int*   cidx   = (int*)(ws + WS_CIDX);
    float* cm     = ws + WS_CM;
    float* cs     = ws + WS_CS;
    float* rM     = ws + WS_RM;
    float* rS     = ws + WS_RS;

    // q2 bf16 hi/lo, FRAGMENT-ORDERED (written by fused mlp_reduce L2)
    unsigned short* q2hg = (unsigned short*)(ws + WS_Q2HL);  // 64*2048 ushorts
    unsigned short* q2lg = q2hg + (size_t)B * D;

    // sub-allocations inside PART:
    int*   cand2 = (int*)(part + WSP_CAND);                   // 64*64
    float* rvals = part + WSP_RVAL;                           // 64*64
    int*   tidx  = (int*)(part + WSP_TIDX);                   // 64*50

    float* outv   = (float*)d_out;
    float* chitta = outv;                                   // [64][50][2048]
    float* attn   = outv + (size_t)B * KTOP * D;            // [64][50000]
    float* oidxf  = attn + (size_t)B * NSEED;               // [64][50] as float

    // MLP layer 1: 64 n-blocks x 8 k-chunks (kcK=256) -> 512 blocks, 2/CU
    gemm64p_kernel<<<64 * 8, 256, 0, stream>>>(query, W1, logits, D, H, 256, 64);
    mlp_reduce_kernel<<<(B * H) / 256, 256, 0, stream>>>(logits, b1, h, H, 8, 1, nullptr, nullptr);
    // MLP layer 2: 32 n-blocks x 8 k-chunks (kcK=512) -> 256 blocks; fused frag-ordered q2 split
    gemm64p_kernel<<<32 * 8, 256, 0, stream>>>(h, W2, logits, H, D, 512, 32);
    mlp_reduce_kernel<<<(B * D) / 256, 256, 0, stream>>>(logits, b2, q2, D, 8, 0, q2hg, q2lg);
    // similarity + gate + bias -> logits (barrier-free, LDS-free, coalesced
    // fragment-ordered A from L2)
    sims_mfma_kernel<<<(NSEED + 63) / 64, 256, 0, stream>>>(q2hg, q2lg, seed, karma, types, vbias, logits);
    // per-chunk stats + top-20 candidates
    chunk_topk_kernel<<<B * NCHUNKS, 64, 0, stream>>>(logits, cm, cs, cval, cidx);
    // per-row merge -> (M, 1/S) + top-NCAND candidate set
    merge_topk_kernel<<<B, 256, 0, stream>>>(cm, cs, cval, cidx, rM, rS, cand2);
    // exact fp64 rescore of candidates
    rescore_kernel<<<dim3(NCAND / 4, B), 256, 0, stream>>>(q2, seed, karma, types, vbias, cand2, rvals);
    // final sorted top-50 indices
    final50_kernel<<<B, 64, 0, stream>>>(rvals, cand2, oidxf, tidx);
    // full attention weights
    weights_kernel<<<dim3((NSEED / 4 + 255) / 256, B), 256, 0, stream>>>(logits, rM, rS, attn);
    // retrieved embeddings
    gather_kernel<<<dim3(KTOP, B), 256, 0, stream>>>(seed, tidx, chitta);
}

// Round 14
// 361.691 us; speedup vs baseline: 1.0048x; 1.0048x over previous
//
#include <hip/hip_runtime.h>
#include <math.h>

// Problem constants
#define B 64
#define D 2048
#define H 4096
#define NSEED 50000
#define KTOP 50
#define NCAND 64            // rescored candidates per row
#define CEMIT 20            // candidates emitted per chunk (P(chunk holds >20 of top-64) ~ 2e-20)
#define NCHUNKS 64          // topk chunks per row
#define CHUNK_SZ 782        // ceil(50000/64)
#define WBLK ((NSEED / 4 + 255) / 256)   // 49 weight-blocks per row

// ws layout (float offsets)
#define WS_LOGITS   0                         // 64*50000 = 3,200,000 (also MLP partials)
#define WS_H        3200000                   // 64*4096  = 262,144
#define WS_Q2       (WS_H + B*H)              // 64*2048  = 131,072
#define WS_PART     (WS_Q2 + B*D)             // 1,048,576 (tidx lives here)
#define WS_CVAL     (WS_PART + 1048576)       // 64*64*20 = 81,920 (region sized 262,144)
#define WS_CIDX     (WS_CVAL + 262144)        // ints
#define WS_CM       (WS_CIDX + 262144)        // 4096
#define WS_CS       (WS_CM + 4096)            // 4096
#define WS_RM       (WS_CS + 4096)            // 64
#define WS_RS       (WS_RM + 64)              // 64
#define WS_Q2HL     (WS_RS + 64)              // q2h+q2l: 2*131072 ushorts = 131,072 floats
// sub-allocations inside the PART region:
#define WSP_TIDX    240000                    // 64*50 ints

typedef short s16x8 __attribute__((ext_vector_type(8)));
typedef float f32x4 __attribute__((ext_vector_type(4)));

// ---------------------------------------------------------------------------
// bf16 split helpers (RNE, used on the q2 producer path)
// ---------------------------------------------------------------------------
__device__ __forceinline__ unsigned short bf16_rne(float x)
{
    unsigned int b = __float_as_uint(x);
    b += 0x7FFFu + ((b >> 16) & 1u);
    return (unsigned short)(b >> 16);
}
__device__ __forceinline__ float bf16_tof(unsigned short h)
{
    return __uint_as_float(((unsigned int)h) << 16);
}

// ---------------------------------------------------------------------------
// MLP GEMM, pipelined fp32 (kept fp32 deliberately — q2 accuracy gates the
// topk-index ordering). C_partial[kc][64][N] = A[64][Kc] @ W[Kc][N]
// (exact round-7 configuration — known-good)
// ---------------------------------------------------------------------------
__global__ __launch_bounds__(256) void gemm64p_kernel(
    const float* __restrict__ A, const float* __restrict__ W,
    float* __restrict__ part, int K, int N, int kcK, int nBlocks)
{
    __shared__ float As[2][32][68];   // [buf][k][m]
    __shared__ float Bs[2][32][68];   // [buf][k][n]

    const int tid = threadIdx.x;
    const int nb = blockIdx.x % nBlocks;
    const int kc = blockIdx.x / nBlocks;
    const int kbeg = kc * kcK;

    const int tidm = tid >> 4;          // 0..15
    const int tidn = tid & 15;          // 0..15
    const int m0 = tidm * 4;
    const int n0 = tidn * 4;

    const int ar0 = tid >> 3, ac0 = tid & 7;    // + second A float4 at row ar0+32
    const int wr0 = tid >> 4, wc0 = tid & 15;   // + second B float4 at k-row wr0+16

    const float* Aptr0 = A + (size_t)ar0 * K + kbeg + ac0 * 4;
    const float* Aptr1 = A + (size_t)(ar0 + 32) * K + kbeg + ac0 * 4;
    const float* Wptr0 = W + (size_t)(kbeg + wr0) * N + nb * 64 + wc0 * 4;
    const float* Wptr1 = W + (size_t)(kbeg + wr0 + 16) * N + nb * 64 + wc0 * 4;

    float acc[4][4];
#pragma unroll
    for (int i = 0; i < 4; ++i)
#pragma unroll
        for (int j = 0; j < 4; ++j) acc[i][j] = 0.f;

    float4 pa0 = *(const float4*)(Aptr0);
    float4 pa1 = *(const float4*)(Aptr1);
    float4 pb0 = *(const float4*)(Wptr0);
    float4 pb1 = *(const float4*)(Wptr1);

    const int nsteps = kcK / 32;
    for (int s = 0; s < nsteps; ++s) {
        const int buf = s & 1;
        As[buf][ac0 * 4 + 0][ar0] = pa0.x;
        As[buf][ac0 * 4 + 1][ar0] = pa0.y;
        As[buf][ac0 * 4 + 2][ar0] = pa0.z;
        As[buf][ac0 * 4 + 3][ar0] = pa0.w;
        As[buf][ac0 * 4 + 0][ar0 + 32] = pa1.x;
        As[buf][ac0 * 4 + 1][ar0 + 32] = pa1.y;
        As[buf][ac0 * 4 + 2][ar0 + 32] = pa1.z;
        As[buf][ac0 * 4 + 3][ar0 + 32] = pa1.w;
        *(float4*)&Bs[buf][wr0][wc0 * 4] = pb0;
        *(float4*)&Bs[buf][wr0 + 16][wc0 * 4] = pb1;
        if (s + 1 < nsteps) {
            const int ko = 32 * (s + 1);
            pa0 = *(const float4*)(Aptr0 + ko);
            pa1 = *(const float4*)(Aptr1 + ko);
            pb0 = *(const float4*)(Wptr0 + (size_t)ko * N);
            pb1 = *(const float4*)(Wptr1 + (size_t)ko * N);
        }
        __syncthreads();
#pragma unroll
        for (int kk = 0; kk < 32; ++kk) {
            float4 a = *(const float4*)&As[buf][kk][m0];
            float4 b = *(const float4*)&Bs[buf][kk][n0];
            float av[4] = {a.x, a.y, a.z, a.w};
            float bv[4] = {b.x, b.y, b.z, b.w};
#pragma unroll
            for (int i = 0; i < 4; ++i)
#pragma unroll
                for (int j = 0; j < 4; ++j)
                    acc[i][j] += av[i] * bv[j];
        }
    }

#pragma unroll
    for (int i = 0; i < 4; ++i) {
        float4 v;
        v.x = acc[i][0]; v.y = acc[i][1]; v.z = acc[i][2]; v.w = acc[i][3];
        *(float4*)(part + (size_t)(kc * B + m0 + i) * N + nb * 64 + n0) = v;
    }
}

// Reduce K-chunk partials + bias (+ optional exact GELU).
// When uh/ul are non-null (layer 2), also emits the bf16 hi/lo split of out.
__global__ void mlp_reduce_kernel(const float* __restrict__ part,
                                  const float* __restrict__ bias,
                                  float* __restrict__ out, int N, int nchunks, int gelu,
                                  unsigned short* __restrict__ uh,
                                  unsigned short* __restrict__ ul)
{
    int e = blockIdx.x * 256 + threadIdx.x;   // over B*N
    int b = e / N, j = e - b * N;
    float s = bias[j];
    for (int c = 0; c < nchunks; ++c)
        s += part[(size_t)(c * B + b) * N + j];
    if (gelu)
        s = 0.5f * s * (1.0f + erff(s * 0.70710678118654752f));
    out[e] = s;
    if (uh) {
        unsigned short h = bf16_rne(s);
        uh[e] = h;
        ul[e] = bf16_rne(s - bf16_tof(h));
    }
}

// int64-layout hedge for vritti_types (values 0..4 -> high words all zero)
__device__ __forceinline__ bool types_is_i64(const int* t)
{
    int acc = 0;
#pragma unroll
    for (int j = 0; j < 16; ++j) acc |= t[2 * j + 1];
    return acc == 0;
}

// ---------------------------------------------------------------------------
// sims via split-bf16 MFMA — round-11 structure (equal-best, lowest VGPR)
// + T5 s_setprio(1) around the MFMA clusters (waves at 4 blocks/CU are
// phase-staggered, so the CU scheduler has load/compute roles to arbitrate).
// ---------------------------------------------------------------------------
__global__ __launch_bounds__(256, 4) void sims_mfma_kernel(
    const unsigned short* __restrict__ q2h, const unsigned short* __restrict__ q2l,
    const float* __restrict__ seed,
    const float* __restrict__ karma, const int* __restrict__ types,
    const float* __restrict__ vbias, float* __restrict__ logits)
{
    __shared__ __align__(16) unsigned short Ash[2][64][72];
    __shared__ __align__(16) unsigned short Asl[2][64][72];

    const int tid = threadIdx.x;
    const int n0 = blockIdx.x * 64;
    const int lane = tid & 63;
    const int wv  = tid >> 6;       // 0..3: n-tile of this wave
    const int l15 = lane & 15;
    const int lg  = lane >> 4;      // k-group 0..3

    const int srow = tid >> 2;      // A staging row 0..63
    const int seg  = tid & 3;       // A staging 16-short segment

    const int nrow = n0 + wv * 16 + l15;            // seed row this lane owns
    const bool nvalid = nrow < NSEED;
    const float* brow = seed + (size_t)nrow * D + 8 * lg;
    const size_t aoff = (size_t)srow * D + 16 * seg;

    f32x4 acc[4];
#pragma unroll
    for (int t = 0; t < 4; ++t) acc[t] = (f32x4){0.f, 0.f, 0.f, 0.f};

    // -------- pipeline registers --------
    s16x8 aha, ahb, ala, alb;       // SINGLE A set (depth-1)
    float4 b00, b01, b02, b03;      // B set 0 (even phases): k +[0,4,32,36]
    float4 b10, b11, b12, b13;      // B set 1 (odd phases)

    aha = *(const s16x8*)(q2h + aoff);
    ahb = *(const s16x8*)(q2h + aoff + 8);
    ala = *(const s16x8*)(q2l + aoff);
    alb = *(const s16x8*)(q2l + aoff + 8);
    b00 = b01 = b02 = b03 = make_float4(0.f, 0.f, 0.f, 0.f);
    b10 = b11 = b12 = b13 = make_float4(0.f, 0.f, 0.f, 0.f);
    if (nvalid) {
        b00 = *(const float4*)(brow);      b01 = *(const float4*)(brow + 4);
        b02 = *(const float4*)(brow + 32); b03 = *(const float4*)(brow + 36);
        b10 = *(const float4*)(brow + 64); b11 = *(const float4*)(brow + 68);
        b12 = *(const float4*)(brow + 96); b13 = *(const float4*)(brow + 100);
    }

#define SIMS_BARRIER() asm volatile("s_waitcnt lgkmcnt(0)\n\ts_barrier" ::: "memory")

#define SIMS_CONV(F0, F1, BH, BL)                                          \
    {                                                                      \
        union { unsigned int w[4]; s16x8 v; } uh_, ul_;                    \
        float xs[8] = {F0.x, F0.y, F0.z, F0.w, F1.x, F1.y, F1.z, F1.w};    \
        _Pragma("unroll")                                                  \
        for (int j = 0; j < 4; ++j) {                                      \
            unsigned int u0 = __float_as_uint(xs[2 * j]);                  \
            unsigned int u1 = __float_as_uint(xs[2 * j + 1]);              \
            unsigned int h0 = u0 & 0xFFFF0000u;                            \
            unsigned int h1 = u1 & 0xFFFF0000u;                            \
            uh_.w[j] = (u0 >> 16) | h1;                                    \
            float r0 = xs[2 * j]     - __uint_as_float(h0);                \
            float r1 = xs[2 * j + 1] - __uint_as_float(h1);                \
            ul_.w[j] = (__float_as_uint(r0) >> 16)                         \
                     | (__float_as_uint(r1) & 0xFFFF0000u);                \
        }                                                                  \
        BH = uh_.v; BL = ul_.v;                                            \
    }

#define SIMS_MFMA(BUF, KS, BH, BL)                                         \
    __builtin_amdgcn_s_setprio(1);                                         \
    _Pragma("unroll")                                                      \
    for (int t = 0; t < 4; ++t) {                                          \
        s16x8 ah = *(const s16x8*)&Ash[BUF][t * 16 + l15][KS * 32 + 8 * lg]; \
        s16x8 al = *(const s16x8*)&Asl[BUF][t * 16 + l15][KS * 32 + 8 * lg]; \
        acc[t] = __builtin_amdgcn_mfma_f32_16x16x32_bf16(ah, BH, acc[t], 0, 0, 0); \
        acc[t] = __builtin_amdgcn_mfma_f32_16x16x32_bf16(al, BH, acc[t], 0, 0, 0); \
        acc[t] = __builtin_amdgcn_mfma_f32_16x16x32_bf16(ah, BL, acc[t], 0, 0, 0); \
    }                                                                      \
    __builtin_amdgcn_s_setprio(0);

    for (int u = 0; u < 16; ++u) {
        // ============ phase 2u (buffer 0, B set 0) ============
        *(s16x8*)&Ash[0][srow][16 * seg]     = aha;
        *(s16x8*)&Ash[0][srow][16 * seg + 8] = ahb;
        *(s16x8*)&Asl[0][srow][16 * seg]     = ala;
        *(s16x8*)&Asl[0][srow][16 * seg + 8] = alb;
        {   // A for phase 2u+1 (always in range: kb <= 1984)
            const int kb = 128 * u + 64;
            aha = *(const s16x8*)(q2h + aoff + kb);
            ahb = *(const s16x8*)(q2h + aoff + kb + 8);
            ala = *(const s16x8*)(q2l + aoff + kb);
            alb = *(const s16x8*)(q2l + aoff + kb + 8);
        }
        float4 n0a = make_float4(0.f, 0.f, 0.f, 0.f), n0b = n0a, n0c = n0a, n0d = n0a;
        if (u < 15 && nvalid) {                    // B for phase 2u+2
            const int kb = 128 * u + 128;
            n0a = *(const float4*)(brow + kb);      n0b = *(const float4*)(brow + kb + 4);
            n0c = *(const float4*)(brow + kb + 32); n0d = *(const float4*)(brow + kb + 36);
        }
        SIMS_BARRIER();
        {
            s16x8 bh, bl;
            SIMS_CONV(b00, b01, bh, bl);
            SIMS_MFMA(0, 0, bh, bl);
            SIMS_CONV(b02, b03, bh, bl);
            SIMS_MFMA(0, 1, bh, bl);
        }
        b00 = n0a; b01 = n0b; b02 = n0c; b03 = n0d;

        // ============ phase 2u+1 (buffer 1, B set 1) ============
        *(s16x8*)&Ash[1][srow][16 * seg]     = aha;
        *(s16x8*)&Ash[1][srow][16 * seg + 8] = ahb;
        *(s16x8*)&Asl[1][srow][16 * seg]     = ala;
        *(s16x8*)&Asl[1][srow][16 * seg + 8] = alb;
        if (u < 15) {                              // A for phase 2u+2
            const int kb = 128 * u + 128;
            aha = *(const s16x8*)(q2h + aoff + kb);
            ahb = *(const s16x8*)(q2h + aoff + kb + 8);
            ala = *(const s16x8*)(q2l + aoff + kb);
            alb = *(const s16x8*)(q2l + aoff + kb + 8);
        }
        float4 n1a = make_float4(0.f, 0.f, 0.f, 0.f), n1b = n1a, n1c = n1a, n1d = n1a;
        if (u < 15 && nvalid) {                    // B for phase 2u+3
            const int kb = 128 * u + 192;
            n1a = *(const float4*)(brow + kb);      n1b = *(const float4*)(brow + kb + 4);
            n1c = *(const float4*)(brow + kb + 32); n1d = *(const float4*)(brow + kb + 36);
        }
        SIMS_BARRIER();
        {
            s16x8 bh, bl;
            SIMS_CONV(b10, b11, bh, bl);
            SIMS_MFMA(1, 0, bh, bl);
            SIMS_CONV(b12, b13, bh, bl);
            SIMS_MFMA(1, 1, bh, bl);
        }
        b10 = n1a; b11 = n1b; b12 = n1c; b13 = n1d;
    }
#undef SIMS_CONV
#undef SIMS_MFMA
#undef SIMS_BARRIER

    // epilogue: gate + vritti bias. D layout: col=lane&15, row=4*lg+reg.
    if (nvalid) {
        const bool i64 = types_is_i64(types);
        float ka = karma[nrow];
        float gate = 1.0f / (1.0f + expf(-(ka + 0.3f) * 10.0f));
        int ty = i64 ? types[2 * nrow] : types[nrow];
        float bias = vbias[ty];
#pragma unroll
        for (int t = 0; t < 4; ++t) {
#pragma unroll
            for (int r = 0; r < 4; ++r) {
                int m = t * 16 + lg * 4 + r;
                logits[(size_t)m * NSEED + nrow] = acc[t][r] * gate + bias;
            }
        }
    }
}

// ---------------------------------------------------------------------------
// Per-(row,chunk): online softmax partial (m,s) + chunk top-CEMIT.
// grid = 64 rows * 64 chunks, 64 threads (1 wave).
// ---------------------------------------------------------------------------
__global__ __launch_bounds__(64) void chunk_topk_kernel(
    const float* __restrict__ logits,
    float* __restrict__ chunk_m, float* __restrict__ chunk_s,
    float* __restrict__ cand_val, int* __restrict__ cand_idx)
{
    const int bid = blockIdx.x;
    const int row = bid >> 6, chunk = bid & 63;
    const int start = chunk * CHUNK_SZ;
    const int end = min(start + CHUNK_SZ, NSEED);
    const int lane = threadIdx.x;
    const float* Lrow = logits + (size_t)row * NSEED;

    float v[13];
#pragma unroll
    for (int j = 0; j < 13; ++j) {
        int e = start + lane + j * 64;
        v[j] = (e < end) ? Lrow[e] : -INFINITY;
    }

    // online (m, s) partial: s = sum exp(2*(l - m))
    float m = v[0];
#pragma unroll
    for (int j = 1; j < 13; ++j) m = fmaxf(m, v[j]);
    float s = 0.f;
#pragma unroll
    for (int j = 0; j < 13; ++j) s += expf(2.f * (v[j] - m));
#pragma unroll
    for (int d = 1; d < 64; d <<= 1) {
        float mo = __shfl_xor(m, d);
        float so = __shfl_xor(s, d);
        float nm = fmaxf(m, mo);
        s = s * expf(2.f * (m - nm)) + so * expf(2.f * (mo - nm));
        m = nm;
    }
    if (lane == 0) { chunk_m[bid] = m; chunk_s[bid] = s; }

    // chunk top-CEMIT via wave-argmax iterations (lower index wins ties)
    for (int it = 0; it < CEMIT; ++it) {
        float bv = v[0]; int bj = 0;
#pragma unroll
        for (int j = 1; j < 13; ++j)
            if (v[j] > bv) { bv = v[j]; bj = j; }
        int bi = start + lane + bj * 64;
#pragma unroll
        for (int d = 1; d < 64; d <<= 1) {
            float ov = __shfl_xor(bv, d);
            int oi = __shfl_xor(bi, d);
            if (ov > bv || (ov == bv && oi < bi)) { bv = ov; bi = oi; }
        }
        if (lane == 0) {
            cand_val[bid * CEMIT + it] = bv;
            cand_idx[bid * CEMIT + it] = bi;
        }
#pragma unroll
        for (int j = 0; j < 13; ++j)
            if (start + lane + j * 64 == bi) v[j] = -INFINITY;
    }
}

// ---------------------------------------------------------------------------
// FUSED per-row tail: (A) stats merge + top-NCAND selection,
// (B) exact fp64 rescore of the NCAND candidates (16 per wave),
// (C) final sorted top-50. grid = 64 rows, 256 threads.
// Replaces merge_topk + rescore + final50 (saves 2 launches + round-trips).
// ---------------------------------------------------------------------------
__global__ __launch_bounds__(256) void fused_topk_kernel(
    const float* __restrict__ chunk_m, const float* __restrict__ chunk_s,
    const float* __restrict__ cand_val, const int* __restrict__ cand_idx,
    const float* __restrict__ q2, const float* __restrict__ seed,
    const float* __restrict__ karma, const int* __restrict__ types,
    const float* __restrict__ vbias,
    float* __restrict__ row_M, float* __restrict__ row_rS,
    float* __restrict__ out_idx_f, int* __restrict__ topk_idx)
{
    const int row = blockIdx.x;
    const int tid = threadIdx.x;
    const int lane = tid & 63, wave = tid >> 6;
    __shared__ float rv[4];
    __shared__ int ri[4];
    __shared__ int   c2s[NCAND];
    __shared__ float rvs[NCAND];

    // ---- phase A: softmax stats merge (wave 0) ----
    if (wave == 0) {
        float m = chunk_m[row * 64 + lane];
        float s = chunk_s[row * 64 + lane];
#pragma unroll
        for (int d = 1; d < 64; d <<= 1) {
            float mo = __shfl_xor(m, d);
            float so = __shfl_xor(s, d);
            float nm = fmaxf(m, mo);
            s = s * expf(2.f * (m - nm)) + so * expf(2.f * (mo - nm));
            m = nm;
        }
        if (lane == 0) { row_M[row] = m; row_rS[row] = 1.0f / s; }
    }

    // ---- phase A': top-NCAND selection over 1280 candidates ----
    float v[5]; int ix[5];
#pragma unroll
    for (int j = 0; j < 5; ++j) {
        int e = tid + j * 256;                      // 1280 = NCHUNKS*CEMIT
        v[j] = cand_val[row * (NCHUNKS * CEMIT) + e];
        ix[j] = cand_idx[row * (NCHUNKS * CEMIT) + e];
    }
    for (int it = 0; it < NCAND; ++it) {
        float bv = v[0]; int bi = ix[0];
#pragma unroll
        for (int j = 1; j < 5; ++j)
            if (v[j] > bv || (v[j] == bv && ix[j] < bi)) { bv = v[j]; bi = ix[j]; }
#pragma unroll
        for (int d = 1; d < 64; d <<= 1) {
            float ov = __shfl_xor(bv, d);
            int oi = __shfl_xor(bi, d);
            if (ov > bv || (ov == bv && oi < bi)) { bv = ov; bi = oi; }
        }
        if (lane == 0) { rv[wave] = bv; ri[wave] = bi; }
        __syncthreads();
        float wv = rv[0]; int wi = ri[0];
#pragma unroll
        for (int w = 1; w < 4; ++w)
            if (rv[w] > wv || (rv[w] == wv && ri[w] < wi)) { wv = rv[w]; wi = ri[w]; }
        __syncthreads();
        if (tid == 0) c2s[it] = wi;
#pragma unroll
        for (int j = 0; j < 5; ++j)
            if (ix[j] == wi) v[j] = -INFINITY;
    }
    __syncthreads();

    // ---- phase B: exact fp64 rescore (16 candidates per wave) ----
    const bool i64 = types_is_i64(types);
    const float* qrow = q2 + (size_t)row * D;
    for (int ci = wave; ci < NCAND; ci += 4) {
        const int idx = c2s[ci];
        const float* srow = seed + (size_t)idx * D;
        double s = 0.0;
#pragma unroll
        for (int i = 0; i < 8; ++i) {
            float4 a = *(const float4*)(qrow + lane * 4 + i * 256);
            float4 b = *(const float4*)(srow + lane * 4 + i * 256);
            s += (double)a.x * (double)b.x + (double)a.y * (double)b.y
               + (double)a.z * (double)b.z + (double)a.w * (double)b.w;
        }
#pragma unroll
        for (int d = 1; d < 64; d <<= 1) s += __shfl_xor(s, d);
        if (lane == 0) {
            float ka = karma[idx];
            float gate = 1.0f / (1.0f + expf(-(ka + 0.3f) * 10.0f));
            int ty = i64 ? types[2 * idx] : types[idx];
            rvs[ci] = (float)s * gate + vbias[ty];
        }
    }
    __syncthreads();

    // ---- phase C: final sorted top-50 (wave 0) ----
    if (wave == 0) {
        float fv = rvs[lane];
        int fx = c2s[lane];
        for (int it = 0; it < KTOP; ++it) {
            float bv = fv; int bi = fx;
#pragma unroll
            for (int d = 1; d < 64; d <<= 1) {
                float ov = __shfl_xor(bv, d);
                int oi = __shfl_xor(bi, d);
                if (ov > bv || (ov == bv && oi < bi)) { bv = ov; bi = oi; }
            }
            if (lane == 0) {
                out_idx_f[row * KTOP + it] = (float)bi;
                topk_idx[row * KTOP + it] = bi;
            }
            if (fx == bi) fv = -INFINITY;
        }
    }
}

// ---------------------------------------------------------------------------
// FUSED weights + gather (independent outputs; blockIdx range split).
// blocks [0, WBLK*B): attention weights; blocks [WBLK*B, +B*KTOP): gather.
// ---------------------------------------------------------------------------
__global__ __launch_bounds__(256) void weights_gather_kernel(
    const float* __restrict__ logits, const float* __restrict__ row_M,
    const float* __restrict__ row_rS, const float* __restrict__ seed,
    const int* __restrict__ topk_idx,
    float* __restrict__ attn, float* __restrict__ chitta)
{
    const int bid = blockIdx.x;
    if (bid < WBLK * B) {
        const int row = bid / WBLK, fb = bid - row * WBLK;
        const int f = fb * 256 + threadIdx.x;
        if (f >= NSEED / 4) return;
        const float M = row_M[row], rS = row_rS[row];
        float4 l = ((const float4*)(logits + (size_t)row * NSEED))[f];
        float4 w;
        w.x = expf(2.f * (l.x - M)) * rS;
        w.y = expf(2.f * (l.y - M)) * rS;
        w.z = expf(2.f * (l.z - M)) * rS;
        w.w = expf(2.f * (l.w - M)) * rS;
        ((float4*)(attn + (size_t)row * NSEED))[f] = w;
    } else {
        const int b2 = bid - WBLK * B;
        const int row = b2 / KTOP, k = b2 - row * KTOP;
        const int idx = topk_idx[row * KTOP + k];
        const float4* src = (const float4*)(seed + (size_t)idx * D);
        float4* dst = (float4*)(chitta + (size_t)(row * KTOP + k) * D);
#pragma unroll
        for (int j = 0; j < 2; ++j)
            dst[threadIdx.x + j * 256] = src[threadIdx.x + j * 256];
    }
}

extern "C" void kernel_launch(void* const* d_in, const int* in_sizes, int n_in,
                              void* d_out, int out_size, void* d_ws, size_t ws_size,
                              hipStream_t stream)
{
    const float* query = (const float*)d_in[0];
    const int*   types = (const int*)d_in[1];
    const float* seed  = (const float*)d_in[2];
    const float* karma = (const float*)d_in[3];
    const float* vbias = (const float*)d_in[4];
    const float* W1    = (const float*)d_in[5];
    const float* b1    = (const float*)d_in[6];
    const float* W2    = (const float*)d_in[7];
    const float* b2    = (const float*)d_in[8];

    float* ws = (float*)d_ws;
    float* logits = ws + WS_LOGITS;   // also MLP partial buffer (freed before sims)
    float* h      = ws + WS_H;
    float* q2     = ws + WS_Q2;
    float* part   = ws + WS_PART;
    float* cval   = ws + WS_CVAL;
    int*   cidx   = (int*)(ws + WS_CIDX);
    float* cm     = ws + WS_CM;
    float* cs     = ws + WS_CS;
    float* rM     = ws + WS_RM;
    float* rS     = ws + WS_RS;

    // q2 bf16 hi/lo (written by fused mlp_reduce L2)
    unsigned short* q2h = (unsigned short*)(ws + WS_Q2HL);   // 64*2048 ushorts
    unsigned short* q2l = q2h + (size_t)B * D;

    int* tidx = (int*)(part + WSP_TIDX);                      // 64*50

    float* outv   = (float*)d_out;
    float* chitta = outv;                                   // [64][50][2048]
    float* attn   = outv + (size_t)B * KTOP * D;            // [64][50000]
    float* oidxf  = attn + (size_t)B * NSEED;               // [64][50] as float

    // MLP layer 1: 64 n-blocks x 8 k-chunks (kcK=256) -> 512 blocks, 2/CU
    gemm64p_kernel<<<64 * 8, 256, 0, stream>>>(query, W1, logits, D, H, 256, 64);
    mlp_reduce_kernel<<<(B * H) / 256, 256, 0, stream>>>(logits, b1, h, H, 8, 1, nullptr, nullptr);
    // MLP layer 2: 32 n-blocks x 8 k-chunks (kcK=512) -> 256 blocks; fused q2 split
    gemm64p_kernel<<<32 * 8, 256, 0, stream>>>(h, W2, logits, H, D, 512, 32);
    mlp_reduce_kernel<<<(B * D) / 256, 256, 0, stream>>>(logits, b2, q2, D, 8, 0, q2h, q2l);
    // similarity + gate + bias -> logits (r11 pipeline + setprio)
    sims_mfma_kernel<<<(NSEED + 63) / 64, 256, 0, stream>>>(q2h, q2l, seed, karma, types, vbias, logits);
    // per-chunk stats + top-20 candidates
    chunk_topk_kernel<<<B * NCHUNKS, 64, 0, stream>>>(logits, cm, cs, cval, cidx);
    // fused: merge -> (M,1/S) + top-NCAND + fp64 rescore + final top-50
    fused_topk_kernel<<<B, 256, 0, stream>>>(cm, cs, cval, cidx, q2, seed, karma, types, vbias,
                                             rM, rS, oidxf, tidx);
    // fused: attention weights + retrieved-embedding gather
    weights_gather_kernel<<<WBLK * B + B * KTOP, 256, 0, stream>>>(
        logits, rM, rS, seed, tidx, attn, chitta);
}

// Round 15
// 316.739 us; speedup vs baseline: 1.1474x; 1.1419x over previous
//
#include <hip/hip_runtime.h>
#include <math.h>

// Problem constants
#define B 64
#define D 2048
#define H 4096
#define NSEED 50000
#define KTOP 50
#define NCAND 64            // rescored candidates per row
#define CEMIT 20            // candidates emitted per chunk (P(chunk holds >20 of top-64) ~ 2e-20)
#define NCHUNKS 64          // topk chunks per row
#define CHUNK_SZ 782        // ceil(50000/64)
#define WBLK ((NSEED / 4 + 255) / 256)   // 49 weight-blocks per row

// ws layout (float offsets)
#define WS_LOGITS   0                         // 64*50000 = 3,200,000 (also MLP partials)
#define WS_H        3200000                   // 64*4096  = 262,144
#define WS_Q2       (WS_H + B*H)              // 64*2048  = 131,072
#define WS_PART     (WS_Q2 + B*D)             // 1,048,576 (cand/rvals/tidx live here)
#define WS_CVAL     (WS_PART + 1048576)       // 64*64*20 = 81,920 (region sized 262,144)
#define WS_CIDX     (WS_CVAL + 262144)        // ints
#define WS_CM       (WS_CIDX + 262144)        // 4096
#define WS_CS       (WS_CM + 4096)            // 4096
#define WS_RM       (WS_CS + 4096)            // 64
#define WS_RS       (WS_RM + 64)              // 64
#define WS_Q2HL     (WS_RS + 64)              // q2h+q2l: 2*131072 ushorts = 131,072 floats
// sub-allocations inside the PART region:
#define WSP_CAND    200000                    // 64*64 ints
#define WSP_RVAL    220000                    // 64*64 floats
#define WSP_TIDX    240000                    // 64*50 ints

typedef short s16x8 __attribute__((ext_vector_type(8)));
typedef float f32x4 __attribute__((ext_vector_type(4)));

// ---------------------------------------------------------------------------
// bf16 split helpers (RNE, used on the q2 producer path)
// ---------------------------------------------------------------------------
__device__ __forceinline__ unsigned short bf16_rne(float x)
{
    unsigned int b = __float_as_uint(x);
    b += 0x7FFFu + ((b >> 16) & 1u);
    return (unsigned short)(b >> 16);
}
__device__ __forceinline__ float bf16_tof(unsigned short h)
{
    return __uint_as_float(((unsigned int)h) << 16);
}

// ---------------------------------------------------------------------------
// MLP GEMM, pipelined fp32 (kept fp32 deliberately — q2 accuracy gates the
// topk-index ordering). C_partial[kc][64][N] = A[64][Kc] @ W[Kc][N]
// (exact round-7 configuration — known-good)
// ---------------------------------------------------------------------------
__global__ __launch_bounds__(256) void gemm64p_kernel(
    const float* __restrict__ A, const float* __restrict__ W,
    float* __restrict__ part, int K, int N, int kcK, int nBlocks)
{
    __shared__ float As[2][32][68];   // [buf][k][m]
    __shared__ float Bs[2][32][68];   // [buf][k][n]

    const int tid = threadIdx.x;
    const int nb = blockIdx.x % nBlocks;
    const int kc = blockIdx.x / nBlocks;
    const int kbeg = kc * kcK;

    const int tidm = tid >> 4;          // 0..15
    const int tidn = tid & 15;          // 0..15
    const int m0 = tidm * 4;
    const int n0 = tidn * 4;

    const int ar0 = tid >> 3, ac0 = tid & 7;    // + second A float4 at row ar0+32
    const int wr0 = tid >> 4, wc0 = tid & 15;   // + second B float4 at k-row wr0+16

    const float* Aptr0 = A + (size_t)ar0 * K + kbeg + ac0 * 4;
    const float* Aptr1 = A + (size_t)(ar0 + 32) * K + kbeg + ac0 * 4;
    const float* Wptr0 = W + (size_t)(kbeg + wr0) * N + nb * 64 + wc0 * 4;
    const float* Wptr1 = W + (size_t)(kbeg + wr0 + 16) * N + nb * 64 + wc0 * 4;

    float acc[4][4];
#pragma unroll
    for (int i = 0; i < 4; ++i)
#pragma unroll
        for (int j = 0; j < 4; ++j) acc[i][j] = 0.f;

    float4 pa0 = *(const float4*)(Aptr0);
    float4 pa1 = *(const float4*)(Aptr1);
    float4 pb0 = *(const float4*)(Wptr0);
    float4 pb1 = *(const float4*)(Wptr1);

    const int nsteps = kcK / 32;
    for (int s = 0; s < nsteps; ++s) {
        const int buf = s & 1;
        As[buf][ac0 * 4 + 0][ar0] = pa0.x;
        As[buf][ac0 * 4 + 1][ar0] = pa0.y;
        As[buf][ac0 * 4 + 2][ar0] = pa0.z;
        As[buf][ac0 * 4 + 3][ar0] = pa0.w;
        As[buf][ac0 * 4 + 0][ar0 + 32] = pa1.x;
        As[buf][ac0 * 4 + 1][ar0 + 32] = pa1.y;
        As[buf][ac0 * 4 + 2][ar0 + 32] = pa1.z;
        As[buf][ac0 * 4 + 3][ar0 + 32] = pa1.w;
        *(float4*)&Bs[buf][wr0][wc0 * 4] = pb0;
        *(float4*)&Bs[buf][wr0 + 16][wc0 * 4] = pb1;
        if (s + 1 < nsteps) {
            const int ko = 32 * (s + 1);
            pa0 = *(const float4*)(Aptr0 + ko);
            pa1 = *(const float4*)(Aptr1 + ko);
            pb0 = *(const float4*)(Wptr0 + (size_t)ko * N);
            pb1 = *(const float4*)(Wptr1 + (size_t)ko * N);
        }
        __syncthreads();
#pragma unroll
        for (int kk = 0; kk < 32; ++kk) {
            float4 a = *(const float4*)&As[buf][kk][m0];
            float4 b = *(const float4*)&Bs[buf][kk][n0];
            float av[4] = {a.x, a.y, a.z, a.w};
            float bv[4] = {b.x, b.y, b.z, b.w};
#pragma unroll
            for (int i = 0; i < 4; ++i)
#pragma unroll
                for (int j = 0; j < 4; ++j)
                    acc[i][j] += av[i] * bv[j];
        }
    }

#pragma unroll
    for (int i = 0; i < 4; ++i) {
        float4 v;
        v.x = acc[i][0]; v.y = acc[i][1]; v.z = acc[i][2]; v.w = acc[i][3];
        *(float4*)(part + (size_t)(kc * B + m0 + i) * N + nb * 64 + n0) = v;
    }
}

// Reduce K-chunk partials + bias (+ optional exact GELU).
// When uh/ul are non-null (layer 2), also emits the bf16 hi/lo split of out.
__global__ void mlp_reduce_kernel(const float* __restrict__ part,
                                  const float* __restrict__ bias,
                                  float* __restrict__ out, int N, int nchunks, int gelu,
                                  unsigned short* __restrict__ uh,
                                  unsigned short* __restrict__ ul)
{
    int e = blockIdx.x * 256 + threadIdx.x;   // over B*N
    int b = e / N, j = e - b * N;
    float s = bias[j];
    for (int c = 0; c < nchunks; ++c)
        s += part[(size_t)(c * B + b) * N + j];
    if (gelu)
        s = 0.5f * s * (1.0f + erff(s * 0.70710678118654752f));
    out[e] = s;
    if (uh) {
        unsigned short h = bf16_rne(s);
        uh[e] = h;
        ul[e] = bf16_rne(s - bf16_tof(h));
    }
}

// int64-layout hedge for vritti_types (values 0..4 -> high words all zero)
__device__ __forceinline__ bool types_is_i64(const int* t)
{
    int acc = 0;
#pragma unroll
    for (int j = 0; j < 16; ++j) acc |= t[2 * j + 1];
    return acc == 0;
}

// ---------------------------------------------------------------------------
// sims via split-bf16 MFMA — exact round-11 structure (equal-best, 318 us):
// K-step 64, single A register set (depth-1, L2-latency covered), depth-2 B
// register pipeline (HBM), truncation-split conversion, raw
// s_barrier+lgkmcnt(0) (no vmcnt drain), __launch_bounds__(256,4).
// NO setprio (measured negative on this barrier-synced structure, r14/m190).
// ---------------------------------------------------------------------------
__global__ __launch_bounds__(256, 4) void sims_mfma_kernel(
    const unsigned short* __restrict__ q2h, const unsigned short* __restrict__ q2l,
    const float* __restrict__ seed,
    const float* __restrict__ karma, const int* __restrict__ types,
    const float* __restrict__ vbias, float* __restrict__ logits)
{
    __shared__ __align__(16) unsigned short Ash[2][64][72];
    __shared__ __align__(16) unsigned short Asl[2][64][72];

    const int tid = threadIdx.x;
    const int n0 = blockIdx.x * 64;
    const int lane = tid & 63;
    const int wv  = tid >> 6;       // 0..3: n-tile of this wave
    const int l15 = lane & 15;
    const int lg  = lane >> 4;      // k-group 0..3

    const int srow = tid >> 2;      // A staging row 0..63
    const int seg  = tid & 3;       // A staging 16-short segment

    const int nrow = n0 + wv * 16 + l15;            // seed row this lane owns
    const bool nvalid = nrow < NSEED;
    const float* brow = seed + (size_t)nrow * D + 8 * lg;
    const size_t aoff = (size_t)srow * D + 16 * seg;

    f32x4 acc[4];
#pragma unroll
    for (int t = 0; t < 4; ++t) acc[t] = (f32x4){0.f, 0.f, 0.f, 0.f};

    // -------- pipeline registers --------
    s16x8 aha, ahb, ala, alb;       // SINGLE A set (depth-1)
    float4 b00, b01, b02, b03;      // B set 0 (even phases): k +[0,4,32,36]
    float4 b10, b11, b12, b13;      // B set 1 (odd phases)

    aha = *(const s16x8*)(q2h + aoff);
    ahb = *(const s16x8*)(q2h + aoff + 8);
    ala = *(const s16x8*)(q2l + aoff);
    alb = *(const s16x8*)(q2l + aoff + 8);
    b00 = b01 = b02 = b03 = make_float4(0.f, 0.f, 0.f, 0.f);
    b10 = b11 = b12 = b13 = make_float4(0.f, 0.f, 0.f, 0.f);
    if (nvalid) {
        b00 = *(const float4*)(brow);      b01 = *(const float4*)(brow + 4);
        b02 = *(const float4*)(brow + 32); b03 = *(const float4*)(brow + 36);
        b10 = *(const float4*)(brow + 64); b11 = *(const float4*)(brow + 68);
        b12 = *(const float4*)(brow + 96); b13 = *(const float4*)(brow + 100);
    }

#define SIMS_BARRIER() asm volatile("s_waitcnt lgkmcnt(0)\n\ts_barrier" ::: "memory")

#define SIMS_CONV(F0, F1, BH, BL)                                          \
    {                                                                      \
        union { unsigned int w[4]; s16x8 v; } uh_, ul_;                    \
        float xs[8] = {F0.x, F0.y, F0.z, F0.w, F1.x, F1.y, F1.z, F1.w};    \
        _Pragma("unroll")                                                  \
        for (int j = 0; j < 4; ++j) {                                      \
            unsigned int u0 = __float_as_uint(xs[2 * j]);                  \
            unsigned int u1 = __float_as_uint(xs[2 * j + 1]);              \
            unsigned int h0 = u0 & 0xFFFF0000u;                            \
            unsigned int h1 = u1 & 0xFFFF0000u;                            \
            uh_.w[j] = (u0 >> 16) | h1;                                    \
            float r0 = xs[2 * j]     - __uint_as_float(h0);                \
            float r1 = xs[2 * j + 1] - __uint_as_float(h1);                \
            ul_.w[j] = (__float_as_uint(r0) >> 16)                         \
                     | (__float_as_uint(r1) & 0xFFFF0000u);                \
        }                                                                  \
        BH = uh_.v; BL = ul_.v;                                            \
    }

#define SIMS_MFMA(BUF, KS, BH, BL)                                         \
    _Pragma("unroll")                                                      \
    for (int t = 0; t < 4; ++t) {                                          \
        s16x8 ah = *(const s16x8*)&Ash[BUF][t * 16 + l15][KS * 32 + 8 * lg]; \
        s16x8 al = *(const s16x8*)&Asl[BUF][t * 16 + l15][KS * 32 + 8 * lg]; \
        acc[t] = __builtin_amdgcn_mfma_f32_16x16x32_bf16(ah, BH, acc[t], 0, 0, 0); \
        acc[t] = __builtin_amdgcn_mfma_f32_16x16x32_bf16(al, BH, acc[t], 0, 0, 0); \
        acc[t] = __builtin_amdgcn_mfma_f32_16x16x32_bf16(ah, BL, acc[t], 0, 0, 0); \
    }

    for (int u = 0; u < 16; ++u) {
        // ============ phase 2u (buffer 0, B set 0) ============
        *(s16x8*)&Ash[0][srow][16 * seg]     = aha;
        *(s16x8*)&Ash[0][srow][16 * seg + 8] = ahb;
        *(s16x8*)&Asl[0][srow][16 * seg]     = ala;
        *(s16x8*)&Asl[0][srow][16 * seg + 8] = alb;
        {   // A for phase 2u+1 (always in range: kb <= 1984)
            const int kb = 128 * u + 64;
            aha = *(const s16x8*)(q2h + aoff + kb);
            ahb = *(const s16x8*)(q2h + aoff + kb + 8);
            ala = *(const s16x8*)(q2l + aoff + kb);
            alb = *(const s16x8*)(q2l + aoff + kb + 8);
        }
        float4 n0a = make_float4(0.f, 0.f, 0.f, 0.f), n0b = n0a, n0c = n0a, n0d = n0a;
        if (u < 15 && nvalid) {                    // B for phase 2u+2
            const int kb = 128 * u + 128;
            n0a = *(const float4*)(brow + kb);      n0b = *(const float4*)(brow + kb + 4);
            n0c = *(const float4*)(brow + kb + 32); n0d = *(const float4*)(brow + kb + 36);
        }
        SIMS_BARRIER();
        {
            s16x8 bh, bl;
            SIMS_CONV(b00, b01, bh, bl);
            SIMS_MFMA(0, 0, bh, bl);
            SIMS_CONV(b02, b03, bh, bl);
            SIMS_MFMA(0, 1, bh, bl);
        }
        b00 = n0a; b01 = n0b; b02 = n0c; b03 = n0d;

        // ============ phase 2u+1 (buffer 1, B set 1) ============
        *(s16x8*)&Ash[1][srow][16 * seg]     = aha;
        *(s16x8*)&Ash[1][srow][16 * seg + 8] = ahb;
        *(s16x8*)&Asl[1][srow][16 * seg]     = ala;
        *(s16x8*)&Asl[1][srow][16 * seg + 8] = alb;
        if (u < 15) {                              // A for phase 2u+2
            const int kb = 128 * u + 128;
            aha = *(const s16x8*)(q2h + aoff + kb);
            ahb = *(const s16x8*)(q2h + aoff + kb + 8);
            ala = *(const s16x8*)(q2l + aoff + kb);
            alb = *(const s16x8*)(q2l + aoff + kb + 8);
        }
        float4 n1a = make_float4(0.f, 0.f, 0.f, 0.f), n1b = n1a, n1c = n1a, n1d = n1a;
        if (u < 15 && nvalid) {                    // B for phase 2u+3
            const int kb = 128 * u + 192;
            n1a = *(const float4*)(brow + kb);      n1b = *(const float4*)(brow + kb + 4);
            n1c = *(const float4*)(brow + kb + 32); n1d = *(const float4*)(brow + kb + 36);
        }
        SIMS_BARRIER();
        {
            s16x8 bh, bl;
            SIMS_CONV(b10, b11, bh, bl);
            SIMS_MFMA(1, 0, bh, bl);
            SIMS_CONV(b12, b13, bh, bl);
            SIMS_MFMA(1, 1, bh, bl);
        }
        b10 = n1a; b11 = n1b; b12 = n1c; b13 = n1d;
    }
#undef SIMS_CONV
#undef SIMS_MFMA
#undef SIMS_BARRIER

    // epilogue: gate + vritti bias. D layout: col=lane&15, row=4*lg+reg.
    if (nvalid) {
        const bool i64 = types_is_i64(types);
        float ka = karma[nrow];
        float gate = 1.0f / (1.0f + expf(-(ka + 0.3f) * 10.0f));
        int ty = i64 ? types[2 * nrow] : types[nrow];
        float bias = vbias[ty];
#pragma unroll
        for (int t = 0; t < 4; ++t) {
#pragma unroll
            for (int r = 0; r < 4; ++r) {
                int m = t * 16 + lg * 4 + r;
                logits[(size_t)m * NSEED + nrow] = acc[t][r] * gate + bias;
            }
        }
    }
}

// ---------------------------------------------------------------------------
// Per-(row,chunk): online softmax partial (m,s) + chunk top-CEMIT.
// grid = 64 rows * 64 chunks, 64 threads (1 wave).
// ---------------------------------------------------------------------------
__global__ __launch_bounds__(64) void chunk_topk_kernel(
    const float* __restrict__ logits,
    float* __restrict__ chunk_m, float* __restrict__ chunk_s,
    float* __restrict__ cand_val, int* __restrict__ cand_idx)
{
    const int bid = blockIdx.x;
    const int row = bid >> 6, chunk = bid & 63;
    const int start = chunk * CHUNK_SZ;
    const int end = min(start + CHUNK_SZ, NSEED);
    const int lane = threadIdx.x;
    const float* Lrow = logits + (size_t)row * NSEED;

    float v[13];
#pragma unroll
    for (int j = 0; j < 13; ++j) {
        int e = start + lane + j * 64;
        v[j] = (e < end) ? Lrow[e] : -INFINITY;
    }

    // online (m, s) partial: s = sum exp(2*(l - m))
    float m = v[0];
#pragma unroll
    for (int j = 1; j < 13; ++j) m = fmaxf(m, v[j]);
    float s = 0.f;
#pragma unroll
    for (int j = 0; j < 13; ++j) s += expf(2.f * (v[j] - m));
#pragma unroll
    for (int d = 1; d < 64; d <<= 1) {
        float mo = __shfl_xor(m, d);
        float so = __shfl_xor(s, d);
        float nm = fmaxf(m, mo);
        s = s * expf(2.f * (m - nm)) + so * expf(2.f * (mo - nm));
        m = nm;
    }
    if (lane == 0) { chunk_m[bid] = m; chunk_s[bid] = s; }

    // chunk top-CEMIT via wave-argmax iterations (lower index wins ties)
    for (int it = 0; it < CEMIT; ++it) {
        float bv = v[0]; int bj = 0;
#pragma unroll
        for (int j = 1; j < 13; ++j)
            if (v[j] > bv) { bv = v[j]; bj = j; }
        int bi = start + lane + bj * 64;
#pragma unroll
        for (int d = 1; d < 64; d <<= 1) {
            float ov = __shfl_xor(bv, d);
            int oi = __shfl_xor(bi, d);
            if (ov > bv || (ov == bv && oi < bi)) { bv = ov; bi = oi; }
        }
        if (lane == 0) {
            cand_val[bid * CEMIT + it] = bv;
            cand_idx[bid * CEMIT + it] = bi;
        }
#pragma unroll
        for (int j = 0; j < 13; ++j)
            if (start + lane + j * 64 == bi) v[j] = -INFINITY;
    }
}

// ---------------------------------------------------------------------------
// Per-row merge: 64 (m,s) partials -> (M, 1/S); 1280 candidates -> top-NCAND
// candidate indices (by MFMA logit; candidate set, not final order).
// ---------------------------------------------------------------------------
__global__ __launch_bounds__(256) void merge_topk_kernel(
    const float* __restrict__ chunk_m, const float* __restrict__ chunk_s,
    const float* __restrict__ cand_val, const int* __restrict__ cand_idx,
    float* __restrict__ row_M, float* __restrict__ row_rS,
    int* __restrict__ cand2)
{
    const int row = blockIdx.x;
    const int tid = threadIdx.x;
    const int lane = tid & 63, wave = tid >> 6;
    __shared__ float rv[4];
    __shared__ int ri[4];

    if (wave == 0) {
        float m = chunk_m[row * 64 + lane];
        float s = chunk_s[row * 64 + lane];
#pragma unroll
        for (int d = 1; d < 64; d <<= 1) {
            float mo = __shfl_xor(m, d);
            float so = __shfl_xor(s, d);
            float nm = fmaxf(m, mo);
            s = s * expf(2.f * (m - nm)) + so * expf(2.f * (mo - nm));
            m = nm;
        }
        if (lane == 0) { row_M[row] = m; row_rS[row] = 1.0f / s; }
    }

    float v[5]; int ix[5];
#pragma unroll
    for (int j = 0; j < 5; ++j) {
        int e = tid + j * 256;                      // 1280 = NCHUNKS*CEMIT
        v[j] = cand_val[row * (NCHUNKS * CEMIT) + e];
        ix[j] = cand_idx[row * (NCHUNKS * CEMIT) + e];
    }

    for (int it = 0; it < NCAND; ++it) {
        float bv = v[0]; int bi = ix[0];
#pragma unroll
        for (int j = 1; j < 5; ++j)
            if (v[j] > bv || (v[j] == bv && ix[j] < bi)) { bv = v[j]; bi = ix[j]; }
#pragma unroll
        for (int d = 1; d < 64; d <<= 1) {
            float ov = __shfl_xor(bv, d);
            int oi = __shfl_xor(bi, d);
            if (ov > bv || (ov == bv && oi < bi)) { bv = ov; bi = oi; }
        }
        if (lane == 0) { rv[wave] = bv; ri[wave] = bi; }
        __syncthreads();
        float wv = rv[0]; int wi = ri[0];
#pragma unroll
        for (int w = 1; w < 4; ++w)
            if (rv[w] > wv || (rv[w] == wv && ri[w] < wi)) { wv = rv[w]; wi = ri[w]; }
        __syncthreads();
        if (tid == 0) cand2[row * NCAND + it] = wi;
#pragma unroll
        for (int j = 0; j < 5; ++j)
            if (ix[j] == wi) v[j] = -INFINITY;
    }
}

// ---------------------------------------------------------------------------
// Exact rescore of candidates: fp64 dot(q2[row], seed[idx]) + fp32 gate/bias.
// grid = (NCAND/4, 64 rows), 256 threads = 4 waves (one candidate per wave).
// ---------------------------------------------------------------------------
__global__ __launch_bounds__(256) void rescore_kernel(
    const float* __restrict__ q2, const float* __restrict__ seed,
    const float* __restrict__ karma, const int* __restrict__ types,
    const float* __restrict__ vbias, const int* __restrict__ cand2,
    float* __restrict__ rvals)
{
    const int row = blockIdx.y;
    const int wv = threadIdx.x >> 6, lane = threadIdx.x & 63;
    const int ci = blockIdx.x * 4 + wv;             // 0..NCAND-1
    const int idx = cand2[row * NCAND + ci];
    const float* qrow = q2 + (size_t)row * D;
    const float* srow = seed + (size_t)idx * D;

    double s = 0.0;
#pragma unroll
    for (int i = 0; i < 8; ++i) {
        float4 a = *(const float4*)(qrow + lane * 4 + i * 256);
        float4 b = *(const float4*)(srow + lane * 4 + i * 256);
        s += (double)a.x * (double)b.x + (double)a.y * (double)b.y
           + (double)a.z * (double)b.z + (double)a.w * (double)b.w;
    }
#pragma unroll
    for (int d = 1; d < 64; d <<= 1) s += __shfl_xor(s, d);

    if (lane == 0) {
        float ka = karma[idx];
        float gate = 1.0f / (1.0f + expf(-(ka + 0.3f) * 10.0f));
        bool i64 = types_is_i64(types);
        int ty = i64 ? types[2 * idx] : types[idx];
        rvals[row * NCAND + ci] = (float)s * gate + vbias[ty];
    }
}

// ---------------------------------------------------------------------------
// Final per-row top-50 (sorted desc, lower index on ties) from NCAND rescored.
// grid = 64, 64 threads (1 wave, one candidate per lane).
// ---------------------------------------------------------------------------
__global__ __launch_bounds__(64) void final50_kernel(
    const float* __restrict__ rvals, const int* __restrict__ cand2,
    float* __restrict__ out_idx_f, int* __restrict__ topk_idx)
{
    const int row = blockIdx.x;
    const int lane = threadIdx.x;

    float v = rvals[row * NCAND + lane];
    int ix = cand2[row * NCAND + lane];

    for (int it = 0; it < KTOP; ++it) {
        float bv = v; int bi = ix;
#pragma unroll
        for (int d = 1; d < 64; d <<= 1) {
            float ov = __shfl_xor(bv, d);
            int oi = __shfl_xor(bi, d);
            if (ov > bv || (ov == bv && oi < bi)) { bv = ov; bi = oi; }
        }
        if (lane == 0) {
            out_idx_f[row * KTOP + it] = (float)bi;
            topk_idx[row * KTOP + it] = bi;
        }
        if (ix == bi) v = -INFINITY;
    }
}

// ---------------------------------------------------------------------------
// FUSED weights + gather (independent outputs; blockIdx range split —
// parallelism-neutral, saves one launch).
// ---------------------------------------------------------------------------
__global__ __launch_bounds__(256) void weights_gather_kernel(
    const float* __restrict__ logits, const float* __restrict__ row_M,
    const float* __restrict__ row_rS, const float* __restrict__ seed,
    const int* __restrict__ topk_idx,
    float* __restrict__ attn, float* __restrict__ chitta)
{
    const int bid = blockIdx.x;
    if (bid < WBLK * B) {
        const int row = bid / WBLK, fb = bid - row * WBLK;
        const int f = fb * 256 + threadIdx.x;
        if (f >= NSEED / 4) return;
        const float M = row_M[row], rS = row_rS[row];
        float4 l = ((const float4*)(logits + (size_t)row * NSEED))[f];
        float4 w;
        w.x = expf(2.f * (l.x - M)) * rS;
        w.y = expf(2.f * (l.y - M)) * rS;
        w.z = expf(2.f * (l.z - M)) * rS;
        w.w = expf(2.f * (l.w - M)) * rS;
        ((float4*)(attn + (size_t)row * NSEED))[f] = w;
    } else {
        const int b2 = bid - WBLK * B;
        const int row = b2 / KTOP, k = b2 - row * KTOP;
        const int idx = topk_idx[row * KTOP + k];
        const float4* src = (const float4*)(seed + (size_t)idx * D);
        float4* dst = (float4*)(chitta + (size_t)(row * KTOP + k) * D);
#pragma unroll
        for (int j = 0; j < 2; ++j)
            dst[threadIdx.x + j * 256] = src[threadIdx.x + j * 256];
    }
}

extern "C" void kernel_launch(void* const* d_in, const int* in_sizes, int n_in,
                              void* d_out, int out_size, void* d_ws, size_t ws_size,
                              hipStream_t stream)
{
    const float* query = (const float*)d_in[0];
    const int*   types = (const int*)d_in[1];
    const float* seed  = (const float*)d_in[2];
    const float* karma = (const float*)d_in[3];
    const float* vbias = (const float*)d_in[4];
    const float* W1    = (const float*)d_in[5];
    const float* b1    = (const float*)d_in[6];
    const float* W2    = (const float*)d_in[7];
    const float* b2    = (const float*)d_in[8];

    float* ws = (float*)d_ws;
    float* logits = ws + WS_LOGITS;   // also MLP partial buffer (freed before sims)
    float* h      = ws + WS_H;
    float* q2     = ws + WS_Q2;
    float* part   = ws + WS_PART;
    float* cval   = ws + WS_CVAL;
    int*   cidx   = (int*)(ws + WS_CIDX);
    float* cm     = ws + WS_CM;
    float* cs     = ws + WS_CS;
    float* rM     = ws + WS_RM;
    float* rS     = ws + WS_RS;

    // q2 bf16 hi/lo (written by fused mlp_reduce L2)
    unsigned short* q2h = (unsigned short*)(ws + WS_Q2HL);   // 64*2048 ushorts
    unsigned short* q2l = q2h + (size_t)B * D;

    // sub-allocations inside PART:
    int*   cand2 = (int*)(part + WSP_CAND);                   // 64*64
    float* rvals = part + WSP_RVAL;                           // 64*64
    int*   tidx  = (int*)(part + WSP_TIDX);                   // 64*50

    float* outv   = (float*)d_out;
    float* chitta = outv;                                   // [64][50][2048]
    float* attn   = outv + (size_t)B * KTOP * D;            // [64][50000]
    float* oidxf  = attn + (size_t)B * NSEED;               // [64][50] as float

    // MLP layer 1: 64 n-blocks x 8 k-chunks (kcK=256) -> 512 blocks, 2/CU
    gemm64p_kernel<<<64 * 8, 256, 0, stream>>>(query, W1, logits, D, H, 256, 64);
    mlp_reduce_kernel<<<(B * H) / 256, 256, 0, stream>>>(logits, b1, h, H, 8, 1, nullptr, nullptr);
    // MLP layer 2: 32 n-blocks x 8 k-chunks (kcK=512) -> 256 blocks; fused q2 split
    gemm64p_kernel<<<32 * 8, 256, 0, stream>>>(h, W2, logits, H, D, 512, 32);
    mlp_reduce_kernel<<<(B * D) / 256, 256, 0, stream>>>(logits, b2, q2, D, 8, 0, q2h, q2l);
    // similarity + gate + bias -> logits (r11 pipeline, no setprio)
    sims_mfma_kernel<<<(NSEED + 63) / 64, 256, 0, stream>>>(q2h, q2l, seed, karma, types, vbias, logits);
    // per-chunk stats + top-20 candidates
    chunk_topk_kernel<<<B * NCHUNKS, 64, 0, stream>>>(logits, cm, cs, cval, cidx);
    // per-row merge -> (M, 1/S) + top-NCAND candidate set
    merge_topk_kernel<<<B, 256, 0, stream>>>(cm, cs, cval, cidx, rM, rS, cand2);
    // exact fp64 rescore of candidates (1024-block parallelism restored)
    rescore_kernel<<<dim3(NCAND / 4, B), 256, 0, stream>>>(q2, seed, karma, types, vbias, cand2, rvals);
    // final sorted top-50 indices
    final50_kernel<<<B, 64, 0, stream>>>(rvals, cand2, oidxf, tidx);
    // fused: attention weights + retrieved-embedding gather
    weights_gather_kernel<<<WBLK * B + B * KTOP, 256, 0, stream>>>(
        logits, rM, rS, seed, tidx, attn, chitta);
}